// Round 1
// baseline (282.344 us; speedup 1.0000x reference)
//
#include <hip/hip_runtime.h>

#define KDIM 1024

typedef _Float16 half8 __attribute__((ext_vector_type(8)));
typedef _Float16 half4 __attribute__((ext_vector_type(4)));
typedef float f32x4 __attribute__((ext_vector_type(4)));

// ---- async global->LDS, 16B per lane. LDS dest = wave-uniform base + lane*16 ----
#if defined(__has_builtin)
#if __has_builtin(__builtin_amdgcn_global_load_lds)
#define HAVE_GLDS 1
#endif
#endif

__device__ __forceinline__ void stage16(const _Float16* g, _Float16* wave_base, int lane) {
#ifdef HAVE_GLDS
  __builtin_amdgcn_global_load_lds(
      (const __attribute__((address_space(1))) void*)g,
      (__attribute__((address_space(3))) void*)wave_base, 16, 0, 0);
#else
  *(half8*)(wave_base + lane * 8) = *(const half8*)g;
#endif
}

// ---------------- cast x (f32 -> f16), 4 elems/thread ----------------
__global__ void cast_x_kernel(const float* __restrict__ x, _Float16* __restrict__ xb) {
  size_t i = ((size_t)blockIdx.x * 256 + threadIdx.x) * 4;
  float4 v = *(const float4*)(x + i);
  half4 h = { (_Float16)v.x, (_Float16)v.y, (_Float16)v.z, (_Float16)v.w };
  *(half4*)(xb + i) = h;
}

// ---------------- transpose-cast weights: Wt[n][k] = W[k][n], f16 ----------------
__global__ void wtrans_kernel(const float* __restrict__ Wq, const float* __restrict__ Wk,
                              const float* __restrict__ Wv, _Float16* __restrict__ Wqt,
                              _Float16* __restrict__ Wkt, _Float16* __restrict__ Wvt) {
  const float* src = blockIdx.z == 0 ? Wq : (blockIdx.z == 1 ? Wk : Wv);
  _Float16* dst = blockIdx.z == 0 ? Wqt : (blockIdx.z == 1 ? Wkt : Wvt);
  __shared__ _Float16 tile[32][33];
  int tx = threadIdx.x & 31, ty = threadIdx.x >> 5;
  int c0 = blockIdx.x * 32, r0 = blockIdx.y * 32;
#pragma unroll
  for (int i = 0; i < 4; i++) {
    int r = r0 + ty + i * 8;
    tile[tx][ty + i * 8] = (_Float16)src[(size_t)r * KDIM + c0 + tx];
  }
  __syncthreads();
#pragma unroll
  for (int i = 0; i < 4; i++) {
    int n = c0 + ty + i * 8;
    dst[(size_t)n * KDIM + r0 + tx] = tile[ty + i * 8][tx];
  }
}

// ---------------- mask -> bitmask (1 bit per (b,q,t), t fastest) ----------------
__global__ void maskbits_kernel(const float* __restrict__ m, unsigned long long* __restrict__ bits) {
  size_t i = (size_t)blockIdx.x * 256 + threadIdx.x;
  unsigned long long b = __ballot(m[i] != 0.0f);
  if ((threadIdx.x & 63) == 0) bits[i >> 6] = b;
}

// ---------------- GEMM: C[M,N] = A[M,K] * Bt[N,K]^T (both row-major, f16) ----------
// 128x128 tile, BK=32, 4 waves (2x2), each wave 64x64 as 4x4 mfma_16x16x32 tiles.
// mode 0: out[b,h,s,d] = C[m=b*1024+s][n=h*64+d] * scale   (Q/K projection)
// mode 1: out[b,h,d,s] = C[m=h*64+d][n=b*1024+s]           (V^T projection)
__global__ __launch_bounds__(256, 2)
void gemm_kernel(const _Float16* __restrict__ A, const _Float16* __restrict__ Bt,
                 _Float16* __restrict__ out, int mode, float scale) {
  __shared__ _Float16 As[128 * 32];
  __shared__ _Float16 Bs[128 * 32];
  int tid = threadIdx.x;
  int lane = tid & 63, w4 = tid >> 6;
  int la = lane & 15, qd = lane >> 4;
  int wm = w4 & 1, wn = w4 >> 1;
  int m0 = blockIdx.y * 128, n0 = blockIdx.x * 128;
  int r = tid >> 2, c = (tid & 3) * 8;  // staging: row tid/4, col (tid%4)*8
  const _Float16* Ag = A + (size_t)(m0 + r) * KDIM + c;
  const _Float16* Bg = Bt + (size_t)(n0 + r) * KDIM + c;
  _Float16* a0 = As + w4 * 512;  // wave-uniform LDS base (bytes w4*1024)
  _Float16* b0 = Bs + w4 * 512;
  f32x4 acc[4][4] = {};
  for (int kt = 0; kt < KDIM; kt += 32) {
    stage16(Ag + kt, a0, lane);
    stage16(Ag + (size_t)64 * KDIM + kt, a0 + 2048, lane);
    stage16(Bg + kt, b0, lane);
    stage16(Bg + (size_t)64 * KDIM + kt, b0 + 2048, lane);
    __syncthreads();
    half8 af[4], bf[4];
#pragma unroll
    for (int mi = 0; mi < 4; mi++)
      af[mi] = *(const half8*)(As + (wm * 64 + mi * 16 + la) * 32 + qd * 8);
#pragma unroll
    for (int ni = 0; ni < 4; ni++)
      bf[ni] = *(const half8*)(Bs + (wn * 64 + ni * 16 + la) * 32 + qd * 8);
#pragma unroll
    for (int mi = 0; mi < 4; mi++)
#pragma unroll
      for (int ni = 0; ni < 4; ni++)
        acc[mi][ni] = __builtin_amdgcn_mfma_f32_16x16x32_f16(af[mi], bf[ni], acc[mi][ni], 0, 0, 0);
    __syncthreads();
  }
#pragma unroll
  for (int mi = 0; mi < 4; mi++)
#pragma unroll
    for (int ni = 0; ni < 4; ni++) {
      f32x4 v = acc[mi][ni];
      int mb = m0 + wm * 64 + mi * 16 + qd * 4;
      int n = n0 + wn * 64 + ni * 16 + la;
#pragma unroll
      for (int rg = 0; rg < 4; rg++) {
        int m = mb + rg;
        _Float16 hv = (_Float16)(v[rg] * scale);
        size_t addr;
        if (mode == 0) {
          int b = m >> 10, s = m & 1023, hh = n >> 6, d = n & 63;
          addr = (((size_t)(b * 16 + hh)) * 1024 + s) * 64 + d;
        } else {
          int b = n >> 10, s = n & 1023, hh = m >> 6, d = m & 63;
          addr = (((size_t)(b * 16 + hh)) * 64 + d) * 1024 + s;
        }
        out[addr] = hv;
      }
    }
}

// ---------------- fused attention ----------------
// grid (qtile=16, h=16, b=8), block 256 = 4 waves x 16 q-rows.
// Unsafe softmax => no online rescale: acc_o = sum_t e*v, rs = sum_t e, divide at end.
__global__ __launch_bounds__(256, 2)
void attn_kernel(const _Float16* __restrict__ Q, const _Float16* __restrict__ K,
                 const _Float16* __restrict__ Vt, const unsigned long long* __restrict__ mbits,
                 float* __restrict__ out) {
  __shared__ _Float16 Ks[2 * 64 * 32];  // [kstep][t][32 d]  (64B rows: conflict-free)
  __shared__ _Float16 Vs[2 * 64 * 32];  // [kstep][d][32 t]
  __shared__ _Float16 Ps[4 * 2 * 16 * 32];  // [wave][kstep][q][32 t]  wave-private
  int tid = threadIdx.x;
  int lane = tid & 63, w4 = tid >> 6;
  int la = lane & 15, qd = lane >> 4;
  int qt = blockIdx.x, h = blockIdx.y, b = blockIdx.z;
  const _Float16* Qp = Q + ((size_t)(b * 16 + h)) * 1024 * 64;
  const _Float16* Kp = K + ((size_t)(b * 16 + h)) * 1024 * 64;
  const _Float16* Vp = Vt + ((size_t)(b * 16 + h)) * 64 * 1024;
  int q0w = qt * 64 + w4 * 16;
  half8 qf[2];
  qf[0] = *(const half8*)(Qp + (size_t)(q0w + la) * 64 + qd * 8);
  qf[1] = *(const half8*)(Qp + (size_t)(q0w + la) * 64 + 32 + qd * 8);
  f32x4 acco[4] = {};
  float rs[4] = {0.f, 0.f, 0.f, 0.f};
  int r = tid >> 2, c = (tid & 3) * 8;
  _Float16* kbase = Ks + w4 * 512;
  _Float16* vbase = Vs + w4 * 512;
  const unsigned long long* mrow = mbits + (size_t)b * 1024 * 16;
  for (int tt = 0; tt < 16; tt++) {
    stage16(Kp + (size_t)(tt * 64 + r) * 64 + c, kbase, lane);
    stage16(Kp + (size_t)(tt * 64 + r) * 64 + 32 + c, kbase + 2048, lane);
    stage16(Vp + (size_t)r * 1024 + tt * 64 + c, vbase, lane);
    stage16(Vp + (size_t)r * 1024 + tt * 64 + 32 + c, vbase + 2048, lane);
    __syncthreads();
    // S = Q K^T (scale folded into Q)
    f32x4 accs[4] = {};
#pragma unroll
    for (int tsub = 0; tsub < 4; tsub++) {
#pragma unroll
      for (int ks = 0; ks < 2; ks++) {
        half8 kf = *(const half8*)(Ks + ks * 2048 + (tsub * 16 + la) * 32 + qd * 8);
        accs[tsub] = __builtin_amdgcn_mfma_f32_16x16x32_f16(qf[ks], kf, accs[tsub], 0, 0, 0);
      }
    }
    unsigned long long mw[4];
#pragma unroll
    for (int rg = 0; rg < 4; rg++)
      mw[rg] = mrow[(size_t)(qt * 64 + w4 * 16 + qd * 4 + rg) * 16 + tt];
    // e = mask ? exp(s) : 0; accumulate row sums; write P (C-layout -> LDS)
#pragma unroll
    for (int tsub = 0; tsub < 4; tsub++) {
      int ks = tsub >> 1;
      int t32 = (tsub & 1) * 16 + la;
      int shift = tsub * 16 + la;
#pragma unroll
      for (int rg = 0; rg < 4; rg++) {
        float e = ((mw[rg] >> shift) & 1ull) ? __expf(accs[tsub][rg]) : 0.0f;
        rs[rg] += e;
        Ps[w4 * 1024 + ks * 512 + (qd * 4 + rg) * 32 + t32] = (_Float16)e;
      }
    }
    // O += P V  (P read back in A-layout; Vt tile gives contiguous b-frags)
#pragma unroll
    for (int ks = 0; ks < 2; ks++) {
      half8 pf = *(const half8*)(Ps + w4 * 1024 + ks * 512 + la * 32 + qd * 8);
#pragma unroll
      for (int nsub = 0; nsub < 4; nsub++) {
        half8 vf = *(const half8*)(Vs + ks * 2048 + (nsub * 16 + la) * 32 + qd * 8);
        acco[nsub] = __builtin_amdgcn_mfma_f32_16x16x32_f16(pf, vf, acco[nsub], 0, 0, 0);
      }
    }
    __syncthreads();
  }
  // denominators: reduce over the 16 lanes of each quad (t mod 16 partitions)
#pragma unroll
  for (int rg = 0; rg < 4; rg++) {
#pragma unroll
    for (int off = 1; off < 16; off <<= 1) rs[rg] += __shfl_xor(rs[rg], off);
  }
  float inv[4];
#pragma unroll
  for (int rg = 0; rg < 4; rg++) inv[rg] = 1.0f / (rs[rg] + 1e-8f);
  float* op = out + (size_t)b * 1024 * 1024 + (size_t)h * 64;
#pragma unroll
  for (int nsub = 0; nsub < 4; nsub++)
#pragma unroll
    for (int rg = 0; rg < 4; rg++) {
      int s = q0w + qd * 4 + rg;
      op[(size_t)s * 1024 + nsub * 16 + la] = acco[nsub][rg] * inv[rg];
    }
}

extern "C" void kernel_launch(void* const* d_in, const int* in_sizes, int n_in,
                              void* d_out, int out_size, void* d_ws, size_t ws_size,
                              hipStream_t stream) {
  (void)in_sizes; (void)n_in; (void)out_size; (void)ws_size;
  const float* x = (const float*)d_in[0];
  const float* am = (const float*)d_in[1];
  const float* Wq = (const float*)d_in[2];
  const float* Wk = (const float*)d_in[3];
  const float* Wv = (const float*)d_in[4];
  float* out = (float*)d_out;

  char* p = (char*)d_ws;
  _Float16* xb = (_Float16*)p;  p += (size_t)8192 * 1024 * 2;   // 16 MB
  _Float16* Wqt = (_Float16*)p; p += (size_t)1024 * 1024 * 2;   // 2 MB
  _Float16* Wkt = (_Float16*)p; p += (size_t)1024 * 1024 * 2;
  _Float16* Wvt = (_Float16*)p; p += (size_t)1024 * 1024 * 2;
  _Float16* Qh = (_Float16*)p;  p += (size_t)8192 * 1024 * 2;   // [b,h,s,d]
  _Float16* Kh = (_Float16*)p;  p += (size_t)8192 * 1024 * 2;   // [b,h,s,d]
  _Float16* Vth = (_Float16*)p; p += (size_t)8192 * 1024 * 2;   // [b,h,d,s]
  unsigned long long* mb = (unsigned long long*)p;              // 1 MB

  cast_x_kernel<<<8192, 256, 0, stream>>>(x, xb);
  wtrans_kernel<<<dim3(32, 32, 3), 256, 0, stream>>>(Wq, Wk, Wv, Wqt, Wkt, Wvt);
  maskbits_kernel<<<32768, 256, 0, stream>>>(am, mb);
  // Q = x Wq (scale 1/8 folded), K = x Wk   : M=8192, N=1024
  gemm_kernel<<<dim3(8, 64), 256, 0, stream>>>(xb, Wqt, Qh, 0, 0.125f);
  gemm_kernel<<<dim3(8, 64), 256, 0, stream>>>(xb, Wkt, Kh, 0, 1.0f);
  // V^T = Wv^T x^T : A = Wvt [1024,1024], Bt = xb [8192,1024] -> M=1024, N=8192
  gemm_kernel<<<dim3(64, 8), 256, 0, stream>>>(Wvt, xb, Vth, 1, 1.0f);
  attn_kernel<<<dim3(16, 16, 8), 256, 0, stream>>>(Qh, Kh, Vth, mb, out);
}